// Round 7
// baseline (36.510 us; speedup 1.0000x reference)
//
#include <hip/hip_runtime.h>

#define PN 2048

typedef __attribute__((ext_vector_type(8))) short short8;
typedef __attribute__((ext_vector_type(4))) float f32x4;

static __device__ __forceinline__ unsigned int pk_bf2(float lo, float hi) {
    unsigned int ul = __float_as_uint(lo);
    unsigned int uh = __float_as_uint(hi);
    ul = (ul + 0x7fffu + ((ul >> 16) & 1u)) >> 16;   // RNE f32->bf16
    uh = (uh + 0x7fffu + ((uh >> 16) & 1u)) >> 16;
    return ul | (uh << 16);
}

// Single GEMM: M[p,k] = dot(X[2p], X[2k+1])/128, T = exp(1+M).
// neg[p] = rowsum_p(T) [excl k==2p+1] + colsum_p(T) [excl row==2p]
// J[p] = log(1e-8+neg[p]) - M[p,p];  out = mean(max(J,0)^2) over 4096
// ws: Neg[2048] (memset 0), cnt (memset 0), Dpos[2048] (always written before read)
// Tile 128 rows x 64 cols, grid (16,32), 256 thr (4 waves), 2 blocks/CU.

__global__ __launch_bounds__(256, 2) void sml_fused(
    const float* __restrict__ X, float* __restrict__ Neg, unsigned int* __restrict__ cnt,
    float* __restrict__ Dpos, float* __restrict__ out)
{
    __shared__ __align__(16) unsigned int A_s[128 * 32];  // bf16[128][64], 16B-slot XOR-swizzled
    __shared__ __align__(16) unsigned int B_s[64 * 32];   // bf16[64][64]
    __shared__ float red[2][128];
    __shared__ float red2[2][64];
    __shared__ unsigned int lastflag;

    const int bx = blockIdx.x, by = blockIdx.y;
    const int t = threadIdx.x;                 // 0..255, 4 waves
    const int lane = t & 63, wid = t >> 6;
    const int wr = wid >> 1, wc = wid & 1;     // wave grid 2x2 over (64-row x 32-col) subtiles
    const int g4 = lane >> 4, rl = lane & 15;

    // staging: thread handles 16B k-slot s of A rows r0+32q (q<4) and B rows r0+32q (q<2)
    const int s  = t & 7;
    const int r0 = t >> 3;

    const float* aptr[4];
    const float* bptr[2];
    #pragma unroll
    for (int q = 0; q < 4; ++q)
        aptr[q] = X + (size_t)(2 * (bx * 128 + r0 + 32 * q)) * 256 + s * 8;
    #pragma unroll
    for (int q = 0; q < 2; ++q)
        bptr[q] = X + (size_t)(2 * (by * 64 + r0 + 32 * q) + 1) * 256 + s * 8;

    f32x4 acc[4][2];
    #pragma unroll
    for (int i = 0; i < 4; ++i)
        #pragma unroll
        for (int j = 0; j < 2; ++j) acc[i][j] = (f32x4){0.f, 0.f, 0.f, 0.f};

    float4 pa[4][2], pb[2][2];
    #pragma unroll
    for (int q = 0; q < 4; ++q) {
        pa[q][0] = *(const float4*)(aptr[q]);
        pa[q][1] = *(const float4*)(aptr[q] + 4);
    }
    #pragma unroll
    for (int q = 0; q < 2; ++q) {
        pb[q][0] = *(const float4*)(bptr[q]);
        pb[q][1] = *(const float4*)(bptr[q] + 4);
    }

    for (int ks = 0; ks < 4; ++ks) {
        __syncthreads();   // previous chunk's LDS reads done
        #pragma unroll
        for (int q = 0; q < 4; ++q) {
            const int r  = r0 + 32 * q;
            const int sw = (s ^ (r & 7)) << 2;
            uint4 wa = { pk_bf2(pa[q][0].x, pa[q][0].y), pk_bf2(pa[q][0].z, pa[q][0].w),
                         pk_bf2(pa[q][1].x, pa[q][1].y), pk_bf2(pa[q][1].z, pa[q][1].w) };
            *(uint4*)&A_s[r * 32 + sw] = wa;
        }
        #pragma unroll
        for (int q = 0; q < 2; ++q) {
            const int r  = r0 + 32 * q;
            const int sw = (s ^ (r & 7)) << 2;
            uint4 wb = { pk_bf2(pb[q][0].x, pb[q][0].y), pk_bf2(pb[q][0].z, pb[q][0].w),
                         pk_bf2(pb[q][1].x, pb[q][1].y), pk_bf2(pb[q][1].z, pb[q][1].w) };
            *(uint4*)&B_s[r * 32 + sw] = wb;
        }
        __syncthreads();
        if (ks < 3) {   // prefetch next fp32 chunk; consumed after next barrier
            const int off = (ks + 1) * 64;
            #pragma unroll
            for (int q = 0; q < 4; ++q) {
                pa[q][0] = *(const float4*)(aptr[q] + off);
                pa[q][1] = *(const float4*)(aptr[q] + off + 4);
            }
            #pragma unroll
            for (int q = 0; q < 2; ++q) {
                pb[q][0] = *(const float4*)(bptr[q] + off);
                pb[q][1] = *(const float4*)(bptr[q] + off + 4);
            }
        }
        #pragma unroll
        for (int kk = 0; kk < 2; ++kk) {
            short8 af[4], bfj[2];
            #pragma unroll
            for (int i = 0; i < 4; ++i) {
                const int r  = wr * 64 + i * 16 + rl;
                const int sl = (kk * 4 + g4) ^ (r & 7);
                af[i] = *(const short8*)&A_s[r * 32 + sl * 4];
            }
            #pragma unroll
            for (int j = 0; j < 2; ++j) {
                const int r  = wc * 32 + j * 16 + rl;
                const int sl = (kk * 4 + g4) ^ (r & 7);
                bfj[j] = *(const short8*)&B_s[r * 32 + sl * 4];
            }
            #pragma unroll
            for (int i = 0; i < 4; ++i)
                #pragma unroll
                for (int j = 0; j < 2; ++j)
                    acc[i][j] = __builtin_amdgcn_mfma_f32_16x16x32_bf16(af[i], bfj[j], acc[i][j], 0, 0, 0);
        }
    }

    // fused epilogue: e = exp(1 + c/128); masked row/col sums; Dpos diagonal extraction
    float rs[4][4];
    float cs[2] = {0.f, 0.f};
    #pragma unroll
    for (int i = 0; i < 4; ++i)
        #pragma unroll
        for (int rg = 0; rg < 4; ++rg) rs[i][rg] = 0.f;

    #pragma unroll
    for (int i = 0; i < 4; ++i) {
        #pragma unroll
        for (int j = 0; j < 2; ++j) {
            const int kg = by * 64 + wc * 32 + j * 16 + rl;       // C/D: col = lane&15 [m89]
            #pragma unroll
            for (int rg = 0; rg < 4; ++rg) {
                const int pg = bx * 128 + wr * 64 + i * 16 + g4 * 4 + rg;  // row = (lane>>4)*4+reg
                const float c = acc[i][j][rg] * (1.f / 128.f);
                const float e = __expf(1.f + c);
                if (kg == pg)   // M[p,p] -> coherent-point store, visible to finisher
                    __hip_atomic_store(&Dpos[pg], c, __ATOMIC_RELAXED, __HIP_MEMORY_SCOPE_AGENT);
                rs[i][rg] += (kg == 2 * pg + 1) ? 0.f : e;   // row-sum exclusion (mask_i)
                cs[j]     += (pg == 2 * kg)     ? 0.f : e;   // col-sum exclusion (mask_j)
            }
        }
    }

    // row reduction: over 16 cols (rl lanes), then across the 2 wc waves via LDS
    #pragma unroll
    for (int i = 0; i < 4; ++i) {
        #pragma unroll
        for (int rg = 0; rg < 4; ++rg) {
            float v = rs[i][rg];
            v += __shfl_xor(v, 1); v += __shfl_xor(v, 2);
            v += __shfl_xor(v, 4); v += __shfl_xor(v, 8);
            if (rl == 0) red[wc][wr * 64 + i * 16 + g4 * 4 + rg] = v;
        }
    }
    // col reduction: over 64 rows of the wave (g4 groups), then across wr waves
    #pragma unroll
    for (int j = 0; j < 2; ++j) {
        float v = cs[j];
        v += __shfl_xor(v, 16); v += __shfl_xor(v, 32);
        if (g4 == 0) red2[wr][wc * 32 + j * 16 + rl] = v;
    }
    __syncthreads();
    if (t < 128)
        atomicAdd(&Neg[bx * 128 + t], red[0][t] + red[1][t]);
    else if (t < 192)
        atomicAdd(&Neg[by * 64 + (t - 128)], red2[0][t - 128] + red2[1][t - 128]);

    // completion: last block of 512 computes the final loss
    __syncthreads();   // drains each wave's outstanding atomics (vmcnt) before counting
    if (t == 0) {
        __threadfence();   // release: write-back local L2 to coherence point
        unsigned int old = __hip_atomic_fetch_add(cnt, 1u, __ATOMIC_ACQ_REL, __HIP_MEMORY_SCOPE_AGENT);
        lastflag = (old == 511u) ? 1u : 0u;
    }
    __syncthreads();
    if (lastflag) {
        __threadfence();   // acquire per-wave: invalidate stale L1/L2 lines
        float local = 0.f;
        #pragma unroll
        for (int i = 0; i < 8; ++i) {
            const int p = t + 256 * i;
            const float neg = Neg[p];
            const float dp  = Dpos[p];
            const float J = __logf(1e-8f + neg) - dp;
            const float v = fmaxf(J, 0.f);
            local += v * v;
        }
        #pragma unroll
        for (int m = 1; m < 64; m <<= 1) local += __shfl_xor(local, m);
        if (lane == 0) red[0][wid] = local;
        __syncthreads();
        if (t == 0)
            out[0] = (red[0][0] + red[0][1] + red[0][2] + red[0][3]) * (1.f / 4096.f);
    }
}

extern "C" void kernel_launch(void* const* d_in, const int* in_sizes, int n_in,
                              void* d_out, int out_size, void* d_ws, size_t ws_size,
                              hipStream_t stream) {
    const float* X = (const float*)d_in[0];
    float* ws   = (float*)d_ws;
    float* Neg  = ws;                          // 2048 floats  (memset 0)
    unsigned int* cnt = (unsigned int*)(ws + PN);  // 1 uint    (memset 0)
    float* Dpos = ws + PN + 256;               // 2048 floats (always written before read)
    float* out  = (float*)d_out;

    hipMemsetAsync(d_ws, 0, (PN + 1) * sizeof(float), stream);
    dim3 g1(16, 32);
    sml_fused<<<g1, dim3(256), 0, stream>>>(X, Neg, cnt, Dpos, out);
}

// Round 8
// 25.522 us; speedup vs baseline: 1.4305x; 1.4305x over previous
//
#include <hip/hip_runtime.h>

#define PN 2048

typedef __attribute__((ext_vector_type(8))) short short8;
typedef __attribute__((ext_vector_type(4))) float f32x4;

static __device__ __forceinline__ unsigned int pk_bf2(float lo, float hi) {
    unsigned int ul = __float_as_uint(lo);
    unsigned int uh = __float_as_uint(hi);
    ul = (ul + 0x7fffu + ((ul >> 16) & 1u)) >> 16;   // RNE f32->bf16
    uh = (uh + 0x7fffu + ((uh >> 16) & 1u)) >> 16;
    return ul | (uh << 16);
}

// Single GEMM: M[p,k] = dot(X[2p], X[2k+1])/128, T = exp(1+M).
// neg[p] = rowsum_p(T)[excl k==2p+1] + colsum_p(T)[excl row==2p];
// J[p] = log(1e-8+neg[p]) - M[p,p]; out = mean(max(J,0)^2).
// ws: cnt (memset 0 per call), Srow[16][2048], Scol[16][2048], Dpos[2048]
// (slice arrays written once per call via relaxed agent atomic stores -> no init).
// Tile 128x128, grid (16,16)=256 blocks, 512 thr (8 waves), fence-free completion.

__global__ __launch_bounds__(512, 2) void sml_fused(
    const float* __restrict__ X, float* __restrict__ Srow, float* __restrict__ Scol,
    float* __restrict__ Dpos, unsigned int* __restrict__ cnt, float* __restrict__ out)
{
    __shared__ __align__(16) unsigned int A_s[128 * 32];  // bf16[128][64], 16B-slot XOR-swizzled
    __shared__ __align__(16) unsigned int B_s[128 * 32];
    __shared__ float red[4][128];
    __shared__ unsigned int lastflag;

    const int bx = blockIdx.x, by = blockIdx.y;
    const int t = threadIdx.x;                 // 0..511, 8 waves
    const int lane = t & 63, wid = t >> 6;
    const int wr = wid >> 2, wc = wid & 3;     // wave grid 2x4 over (64-row x 32-col) subtiles
    const int g4 = lane >> 4, rl = lane & 15;

    // staging: thread handles 16B k-slot s of rows r0 + 64q (q=0,1), A (even rows) B (odd rows)
    const int s  = t & 7;
    const int r0 = t >> 3;

    const float* aptr[2];
    const float* bptr[2];
    #pragma unroll
    for (int q = 0; q < 2; ++q) {
        const int r = r0 + 64 * q;
        aptr[q] = X + (size_t)(2 * (bx * 128 + r)) * 256 + s * 8;
        bptr[q] = X + (size_t)(2 * (by * 128 + r) + 1) * 256 + s * 8;
    }

    f32x4 acc[4][2];
    #pragma unroll
    for (int i = 0; i < 4; ++i)
        #pragma unroll
        for (int j = 0; j < 2; ++j) acc[i][j] = (f32x4){0.f, 0.f, 0.f, 0.f};

    float4 pa[2][2], pb[2][2];
    #pragma unroll
    for (int q = 0; q < 2; ++q) {
        pa[q][0] = *(const float4*)(aptr[q]);
        pa[q][1] = *(const float4*)(aptr[q] + 4);
        pb[q][0] = *(const float4*)(bptr[q]);
        pb[q][1] = *(const float4*)(bptr[q] + 4);
    }

    for (int ks = 0; ks < 4; ++ks) {
        __syncthreads();   // previous chunk's LDS reads done
        #pragma unroll
        for (int q = 0; q < 2; ++q) {
            const int r  = r0 + 64 * q;
            const int sw = (s ^ (r & 7)) << 2;
            uint4 wa = { pk_bf2(pa[q][0].x, pa[q][0].y), pk_bf2(pa[q][0].z, pa[q][0].w),
                         pk_bf2(pa[q][1].x, pa[q][1].y), pk_bf2(pa[q][1].z, pa[q][1].w) };
            uint4 wb = { pk_bf2(pb[q][0].x, pb[q][0].y), pk_bf2(pb[q][0].z, pb[q][0].w),
                         pk_bf2(pb[q][1].x, pb[q][1].y), pk_bf2(pb[q][1].z, pb[q][1].w) };
            *(uint4*)&A_s[r * 32 + sw] = wa;
            *(uint4*)&B_s[r * 32 + sw] = wb;
        }
        __syncthreads();
        if (ks < 3) {   // prefetch next fp32 chunk; consumed after next barrier
            const int off = (ks + 1) * 64;
            #pragma unroll
            for (int q = 0; q < 2; ++q) {
                pa[q][0] = *(const float4*)(aptr[q] + off);
                pa[q][1] = *(const float4*)(aptr[q] + off + 4);
                pb[q][0] = *(const float4*)(bptr[q] + off);
                pb[q][1] = *(const float4*)(bptr[q] + off + 4);
            }
        }
        #pragma unroll
        for (int kk = 0; kk < 2; ++kk) {
            short8 af[4], bfj[2];
            #pragma unroll
            for (int i = 0; i < 4; ++i) {
                const int r  = wr * 64 + i * 16 + rl;
                const int sl = (kk * 4 + g4) ^ (r & 7);
                af[i] = *(const short8*)&A_s[r * 32 + sl * 4];
            }
            #pragma unroll
            for (int j = 0; j < 2; ++j) {
                const int r  = wc * 32 + j * 16 + rl;
                const int sl = (kk * 4 + g4) ^ (r & 7);
                bfj[j] = *(const short8*)&B_s[r * 32 + sl * 4];
            }
            #pragma unroll
            for (int i = 0; i < 4; ++i)
                #pragma unroll
                for (int j = 0; j < 2; ++j)
                    acc[i][j] = __builtin_amdgcn_mfma_f32_16x16x32_bf16(af[i], bfj[j], acc[i][j], 0, 0, 0);
        }
    }

    // fused epilogue: e = exp(1 + c/128); masked row/col sums; Dpos diagonal extraction
    float rs[4][4];
    float cs[2] = {0.f, 0.f};
    #pragma unroll
    for (int i = 0; i < 4; ++i)
        #pragma unroll
        for (int rg = 0; rg < 4; ++rg) rs[i][rg] = 0.f;

    #pragma unroll
    for (int i = 0; i < 4; ++i) {
        #pragma unroll
        for (int j = 0; j < 2; ++j) {
            const int kg = by * 128 + wc * 32 + j * 16 + rl;      // C/D: col = lane&15 [m89]
            #pragma unroll
            for (int rg = 0; rg < 4; ++rg) {
                const int pg = bx * 128 + wr * 64 + i * 16 + g4 * 4 + rg;  // row = (lane>>4)*4+reg
                const float c = acc[i][j][rg] * (1.f / 128.f);
                const float e = __expf(1.f + c);
                if (kg == pg)   // M[p,p] -> coherent store, no fence needed
                    __hip_atomic_store(&Dpos[pg], c, __ATOMIC_RELAXED, __HIP_MEMORY_SCOPE_AGENT);
                rs[i][rg] += (kg == 2 * pg + 1) ? 0.f : e;   // row-sum exclusion (mask_i)
                cs[j]     += (pg == 2 * kg)     ? 0.f : e;   // col-sum exclusion (mask_j)
            }
        }
    }

    // row reduction: over 16 cols (rl lanes), then across the 4 wc waves via LDS
    #pragma unroll
    for (int i = 0; i < 4; ++i) {
        #pragma unroll
        for (int rg = 0; rg < 4; ++rg) {
            float v = rs[i][rg];
            v += __shfl_xor(v, 1); v += __shfl_xor(v, 2);
            v += __shfl_xor(v, 4); v += __shfl_xor(v, 8);
            if (rl == 0) red[wc][wr * 64 + i * 16 + g4 * 4 + rg] = v;
        }
    }
    __syncthreads();
    if (t < 128)
        __hip_atomic_store(&Srow[by * PN + bx * 128 + t],
                           red[0][t] + red[1][t] + red[2][t] + red[3][t],
                           __ATOMIC_RELAXED, __HIP_MEMORY_SCOPE_AGENT);
    __syncthreads();   // before reusing red

    // col reduction: over 64 rows of the wave (g4 groups), then across wr waves
    #pragma unroll
    for (int j = 0; j < 2; ++j) {
        float v = cs[j];
        v += __shfl_xor(v, 16); v += __shfl_xor(v, 32);
        if (g4 == 0) red[wr][wc * 32 + j * 16 + rl] = v;
    }
    __syncthreads();
    if (t < 128)
        __hip_atomic_store(&Scol[bx * PN + by * 128 + t],
                           red[0][t] + red[1][t],
                           __ATOMIC_RELAXED, __HIP_MEMORY_SCOPE_AGENT);

    // completion: barrier's implicit vmcnt(0) drains the coherent stores (release for free)
    __syncthreads();
    if (t == 0) {
        unsigned int old = __hip_atomic_fetch_add(cnt, 1u, __ATOMIC_RELAXED, __HIP_MEMORY_SCOPE_AGENT);
        lastflag = (old == 255u) ? 1u : 0u;
    }
    __syncthreads();
    if (lastflag) {
        // last block: all 256 blocks' coherent stores completed before their counter bump
        float local = 0.f;
        #pragma unroll
        for (int i = 0; i < 4; ++i) {
            const int p = t + 512 * i;
            float neg = 0.f;
            #pragma unroll
            for (int g = 0; g < 16; ++g)
                neg += __hip_atomic_load(&Srow[g * PN + p], __ATOMIC_RELAXED, __HIP_MEMORY_SCOPE_AGENT);
            #pragma unroll
            for (int g = 0; g < 16; ++g)
                neg += __hip_atomic_load(&Scol[g * PN + p], __ATOMIC_RELAXED, __HIP_MEMORY_SCOPE_AGENT);
            const float dp = __hip_atomic_load(&Dpos[p], __ATOMIC_RELAXED, __HIP_MEMORY_SCOPE_AGENT);
            const float J = __logf(1e-8f + neg) - dp;
            const float v = fmaxf(J, 0.f);
            local += v * v;
        }
        #pragma unroll
        for (int m = 1; m < 64; m <<= 1) local += __shfl_xor(local, m);
        if (lane == 0) red[0][wid] = local;
        __syncthreads();
        if (t == 0) {
            float ssum = 0.f;
            #pragma unroll
            for (int w = 0; w < 8; ++w) ssum += red[0][w];
            out[0] = ssum * (1.f / 4096.f);
        }
    }
}

extern "C" void kernel_launch(void* const* d_in, const int* in_sizes, int n_in,
                              void* d_out, int out_size, void* d_ws, size_t ws_size,
                              hipStream_t stream) {
    const float* X = (const float*)d_in[0];
    float* ws   = (float*)d_ws;
    unsigned int* cnt = (unsigned int*)ws;     // 1 uint (memset 0 each call)
    float* Srow = ws + 64;                     // 16*2048
    float* Scol = Srow + 16 * PN;              // 16*2048
    float* Dpos = Scol + 16 * PN;              // 2048 (always written before read)
    float* out  = (float*)d_out;

    hipMemsetAsync(cnt, 0, sizeof(unsigned int), stream);
    dim3 g1(16, 16);
    sml_fused<<<g1, dim3(512), 0, stream>>>(X, Srow, Scol, Dpos, cnt, out);
}